// Round 6
// baseline (235.546 us; speedup 1.0000x reference)
//
#include <hip/hip_runtime.h>
#include <hip/hip_bf16.h>

// Problem constants
#define Bb   16
#define Cc   384
#define Nn   1024
#define NH   8
#define HD   48
#define C3   1152
#define D64  64          // padded head dim for MFMA

typedef _Float16 f16x8 __attribute__((ext_vector_type(8)));
typedef __fp16   h16x2 __attribute__((ext_vector_type(2)));
typedef float    f32x4 __attribute__((ext_vector_type(4)));
typedef unsigned short ushort8 __attribute__((ext_vector_type(8)));

__device__ inline unsigned short f2h(float f) {
  union { _Float16 h; unsigned short u; } cv;
  cv.h = (_Float16)f;            // v_cvt_f16_f32, RNE
  return cv.u;
}
__device__ inline unsigned int pk2u(float a, float b) {
  union { h16x2 v; unsigned int u; } cv;
  cv.v = __builtin_amdgcn_cvt_pkrtz(a, b);   // v_cvt_pkrtz_f16_f32
  return cv.u;
}
// v_permlane16_swap_b32: a.row1<->b.row0, a.row3<->b.row2 (16-lane rows)
__device__ inline void plswap(unsigned int &a, unsigned int &b) {
  asm("v_permlane16_swap_b32 %0, %1" : "+v"(a), "+v"(b));
}
__device__ inline f16x8 mk8(unsigned int a, unsigned int b,
                            unsigned int c, unsigned int d) {
  union { unsigned int u[4]; f16x8 h; } cv;
  cv.u[0] = a; cv.u[1] = b; cv.u[2] = c; cv.u[3] = d;
  return cv.h;
}

// async 16B global->LDS; lds dest = wave-uniform base + lane*16.
__device__ inline void gload_lds16(const unsigned short* g, unsigned short* l) {
  __builtin_amdgcn_global_load_lds(
      (const __attribute__((address_space(1))) void*)g,
      (__attribute__((address_space(3))) void*)l, 16, 0, 0);
}

// ---------------------------------------------------------------------------
// Kernel A: prep — weights fp32 -> f16, VhT pad rows (48=ones f16, 49..63=0).
// ---------------------------------------------------------------------------
__global__ __launch_bounds__(256) void prep_kernel(
    const float* __restrict__ qkv_w, const float* __restrict__ pw,
    unsigned short* __restrict__ wqh, unsigned short* __restrict__ pwh,
    unsigned short* __restrict__ vt) {
  const int bid = blockIdx.x;
  if (bid < 1728) {
    int i = bid * 256 + threadIdx.x;
    wqh[i] = f2h(qkv_w[i]);
  } else if (bid < 2304) {
    int i = (bid - 1728) * 256 + threadIdx.x;
    pwh[i] = f2h(pw[i]);
  } else {
    int idx8 = (bid - 2304) * 256 + threadIdx.x;   // 262144 ushort8 chunks
    int bh = idx8 >> 11;
    int rem = idx8 & 2047;
    int row = 48 + (rem >> 7);
    int col = (rem & 127) * 8;
    unsigned short fill = (row == 48) ? (unsigned short)0x3C00 : (unsigned short)0;
    ushort8 v;
#pragma unroll
    for (int j = 0; j < 8; j++) v[j] = fill;
    *(ushort8*)(vt + (size_t)bh * D64 * Nn + (size_t)row * Nn + col) = v;
  }
}

// ---------------------------------------------------------------------------
// Kernel B: x [B][C][N] fp32 -> xT [B][N][C] f16 (transpose + convert).
// ---------------------------------------------------------------------------
__global__ __launch_bounds__(256) void xsplit_kernel(
    const float* __restrict__ x, unsigned short* __restrict__ xh) {
  __shared__ float tile[64][65];
  const int b  = blockIdx.z;
  const int c0 = blockIdx.y * 64;
  const int n0 = blockIdx.x * 64;
  const int t  = threadIdx.x;
  const int rl = t >> 2, sc = (t & 3) * 16;
  {
    const float* src = x + ((size_t)b * Cc + c0 + rl) * Nn + n0 + sc;
#pragma unroll
    for (int i = 0; i < 4; i++) {
      float4 v = *(const float4*)(src + i * 4);
      tile[rl][sc + i * 4 + 0] = v.x; tile[rl][sc + i * 4 + 1] = v.y;
      tile[rl][sc + i * 4 + 2] = v.z; tile[rl][sc + i * 4 + 3] = v.w;
    }
  }
  __syncthreads();
  {
    ushort8 h0, h1;
#pragma unroll
    for (int i = 0; i < 8; i++) h0[i] = f2h(tile[sc + i][rl]);
#pragma unroll
    for (int i = 0; i < 8; i++) h1[i] = f2h(tile[sc + 8 + i][rl]);
    size_t dst = ((size_t)b * Nn + n0 + rl) * Cc + c0 + sc;
    *(ushort8*)(xh + dst) = h0; *(ushort8*)(xh + dst + 8) = h1;
  }
}

// ---------------------------------------------------------------------------
// Kernel C: QKV GEMM, f16 MFMA, j-tile = 96 = exactly 2 heads.
//  q-epilogue folds temp[h]*log2e into the L2-norm scale, so attn's exp2
//  input is the raw MFMA output (no per-element fma on the attn hot path).
// ---------------------------------------------------------------------------
__global__ __launch_bounds__(256, 4) void qkv_mfma(
    const unsigned short* __restrict__ wh,
    const unsigned short* __restrict__ xh,
    const float* __restrict__ bias, const float* __restrict__ temp,
    unsigned short* __restrict__ qh, unsigned short* __restrict__ kh,
    unsigned short* __restrict__ vt) {
  __shared__ unsigned short lds[128 * 136];
  unsigned short* Ash = lds;          // [96][64]
  unsigned short* Bsh = lds + 6144;   // [128][64]

  const int b  = blockIdx.z;
  const int yb = blockIdx.y;
  const int j0 = yb * 96;
  const int n0 = blockIdx.x * 128;
  const int tid = threadIdx.x;
  const int wave = tid >> 6, lane = tid & 63;
  const int quad = lane >> 4, l16 = lane & 15;
  const int wm = (wave >> 1) * 48, wn = (wave & 1) * 64;
  const int hs = wave >> 1;           // head-sub within the 2-head tile

  f32x4 acc[3][4];
#pragma unroll
  for (int mi = 0; mi < 3; mi++)
#pragma unroll
    for (int ni = 0; ni < 4; ni++) acc[mi][ni] = (f32x4){0.f, 0.f, 0.f, 0.f};

  const int sw = l16 & 7;

  for (int c0 = 0; c0 < Cc; c0 += 64) {
    __syncthreads();
#pragma unroll
    for (int s = 0; s < 3; s++) {
      int r  = s * 32 + wave * 8 + (lane >> 3);
      int cg = ((lane & 7) ^ (lane >> 3)) * 8;
      gload_lds16(wh + (size_t)(j0 + r) * Cc + c0 + cg,
                  &Ash[(s * 32 + wave * 8) * 64]);
    }
#pragma unroll
    for (int s = 0; s < 4; s++) {
      int r  = s * 32 + wave * 8 + (lane >> 3);
      int cg = ((lane & 7) ^ (lane >> 3)) * 8;
      gload_lds16(xh + ((size_t)b * Nn + n0 + r) * Cc + c0 + cg,
                  &Bsh[(s * 32 + wave * 8) * 64]);
    }
    __syncthreads();

#pragma unroll
    for (int ks = 0; ks < 64; ks += 32) {
      const int ach = (((ks >> 3) + quad) ^ sw) * 8;
      f16x8 ah[3], bh[4];
#pragma unroll
      for (int mi = 0; mi < 3; mi++)
        ah[mi] = *(const f16x8*)&Ash[(wm + mi * 16 + l16) * 64 + ach];
#pragma unroll
      for (int ni = 0; ni < 4; ni++)
        bh[ni] = *(const f16x8*)&Bsh[(wn + ni * 16 + l16) * 64 + ach];
#pragma unroll
      for (int mi = 0; mi < 3; mi++)
#pragma unroll
        for (int ni = 0; ni < 4; ni++)
          acc[mi][ni] = __builtin_amdgcn_mfma_f32_16x16x32_f16(ah[mi], bh[ni], acc[mi][ni], 0, 0, 0);
    }
  }

  const int part = yb >> 2;           // 0=q, 1=k, 2=v
  const int tq   = yb & 3;            // tile within part -> heads 2tq, 2tq+1
  float bv[3][4];
#pragma unroll
  for (int mi = 0; mi < 3; mi++)
#pragma unroll
    for (int r = 0; r < 4; r++)
      bv[mi][r] = bias[j0 + wm + mi * 16 + quad * 4 + r];

  if (part < 2) {
    unsigned short* dst = part ? kh : qh;
    // q rows additionally carry temp[h]*log2(e)
    const float tmul = part ? 1.0f : temp[2 * tq + hs] * 1.44269504f;
    __syncthreads();   // lds reuse: staging -> transpose buffer
#pragma unroll
    for (int ni = 0; ni < 4; ni++) {
      float vals[3][4];
      float ss = 0.f;
#pragma unroll
      for (int mi = 0; mi < 3; mi++)
#pragma unroll
        for (int r = 0; r < 4; r++) {
          float v = acc[mi][ni][r] + bv[mi][r];
          vals[mi][r] = v; ss += v * v;
        }
      ss += __shfl_xor(ss, 16);       // sum the 4 quads -> full 48-d row norm
      ss += __shfl_xor(ss, 32);
      float scale = tmul / fmaxf(sqrtf(ss), 1e-12f);
      int n = wn + ni * 16 + l16;
#pragma unroll
      for (int mi = 0; mi < 3; mi++) {
        ushort4 sv;
        sv.x = f2h(vals[mi][0] * scale);
        sv.y = f2h(vals[mi][1] * scale);
        sv.z = f2h(vals[mi][2] * scale);
        sv.w = f2h(vals[mi][3] * scale);
        *(ushort4*)&lds[n * 136 + hs * 64 + mi * 16 + quad * 4] = sv;
      }
    }
    {  // zero the d=48..63 pads (full-line stores below include them)
      int n = tid >> 1, h2 = tid & 1;
      ushort8 z = {0, 0, 0, 0, 0, 0, 0, 0};
      *(ushort8*)&lds[n * 136 + h2 * 64 + 48] = z;
      *(ushort8*)&lds[n * 136 + h2 * 64 + 56] = z;
    }
    __syncthreads();
#pragma unroll
    for (int it = 0; it < 8; it++) {
      int n = wave * 32 + it * 4 + (lane >> 4);
      int chunk = lane & 15;
      int hs3 = chunk >> 3, c8 = (chunk & 7) * 8;
      int h = 2 * tq + hs3;
      ushort8 v = *(const ushort8*)&lds[n * 136 + hs3 * 64 + c8];
      *(ushort8*)(dst + ((size_t)(b * NH + h) * Nn + n0 + n) * D64 + c8) = v;
    }
  } else {
    const int h = 2 * tq + hs;
#pragma unroll
    for (int mi = 0; mi < 3; mi++) {
#pragma unroll
      for (int r = 0; r < 4; r++) {
        int d = mi * 16 + quad * 4 + r;
        unsigned short* vrow = vt + ((size_t)(b * NH + h) * D64 + d) * Nn;
#pragma unroll
        for (int ni = 0; ni < 4; ni++) {
          int n = n0 + wn + ni * 16 + l16;
          vrow[n] = f2h(acc[mi][ni][r] + bv[mi][r]);
        }
      }
    }
  }
}

// ---------------------------------------------------------------------------
// Kernel E: f16 MFMA flash attention v6 — NO LDS, direct L2-register path.
//  Diagnosis (R5): latency-bound; barrier-lockstep serialized the phases.
//  K,V per head = 256 KB -> L2-resident (m169: staging L2-fit data is pure
//  overhead). Read K/V fragments straight from global into registers:
//  - zero barriers -> waves free-run at different phases (TLP latency hiding)
//  - zero LDS -> no bank conflicts, no DMA drains
//  - kf/vf transient per g-block to keep VGPR <= 128 (4 waves/SIMD)
//  - temp*log2e pre-folded into Q; denominator via ones-column of V^T.
// ---------------------------------------------------------------------------
__global__ __launch_bounds__(256, 4) void attn_mfma(
    const unsigned short* __restrict__ qh, const unsigned short* __restrict__ kh,
    const unsigned short* __restrict__ vt,
    unsigned short* __restrict__ obh) {
  const int bid = blockIdx.x;
  const int hb = bid & 127;            // same head -> same XCD (bid%8 const)
  const int q0 = (bid >> 7) * 128;
  const int b = hb >> 3, h = hb & 7;
  const int tid = threadIdx.x;
  const int wave = tid >> 6, lane = tid & 63;
  const int quad = lane >> 4, l16 = lane & 15;
  const int qsw = ((quad & 1) << 1) | (quad >> 1);   // swap quads 1<->2

  const size_t headQ = ((size_t)(b * NH + h) * Nn) * D64;
  const unsigned short* Qg = qh + headQ + (size_t)(q0 + wave * 32) * D64;
  const unsigned short* Kg = kh + headQ;
  const unsigned short* Vg = vt + ((size_t)(b * NH + h) * D64) * Nn;

  f16x8 qa0[2], qa1[2];
#pragma unroll
  for (int m = 0; m < 2; m++) {
    qa0[m] = *(const f16x8*)(Qg + (m * 16 + l16) * D64 + quad * 8);
    qa1[m] = *(const f16x8*)(Qg + (m * 16 + l16) * D64 + quad * 8 + 32);
  }

  f32x4 oacc[2][4];
#pragma unroll
  for (int m = 0; m < 2; m++)
#pragma unroll
    for (int g = 0; g < 4; g++) oacc[m][g] = (f32x4){0.f, 0.f, 0.f, 0.f};
  const f32x4 zf = (f32x4){0.f, 0.f, 0.f, 0.f};

  // per-lane fragment bases (advance by tile inside the loop)
  const unsigned short* Kl = Kg + (size_t)l16 * D64 + quad * 8;  // + key*D64
  const unsigned short* Vl = Vg + (size_t)l16 * Nn + qsw * 8;    // + d*Nn + col

  for (int kt = 0; kt < Nn / 64; kt++) {
    const unsigned short* Kt0 = Kl + (size_t)(kt * 64) * D64;
    const unsigned short* Vt0 = Vl + kt * 64;

    // QK^T (swapped): sT[m][g] = S^T[key g*16+quad*4+r][query m*16+l16]
    f32x4 sT[2][4];
    __builtin_amdgcn_s_setprio(1);
#pragma unroll
    for (int g = 0; g < 4; g++) {
      const unsigned short* kb = Kt0 + (size_t)(g * 16) * D64;
      f16x8 kf0 = *(const f16x8*)kb;
      f16x8 kf1 = *(const f16x8*)(kb + 32);
#pragma unroll
      for (int m = 0; m < 2; m++) {
        f32x4 s = __builtin_amdgcn_mfma_f32_16x16x32_f16(kf0, qa0[m], zf, 0, 0, 0);
        sT[m][g] = __builtin_amdgcn_mfma_f32_16x16x32_f16(kf1, qa1[m], s, 0, 0, 0);
      }
    }
    __builtin_amdgcn_s_setprio(0);

    // softmax: exp2 + pack + quad redistribution (per m, keeps VGPR low)
    f16x8 pa[2][2];
#pragma unroll
    for (int m = 0; m < 2; m++) {
      unsigned int w0[4], w1[4];
#pragma unroll
      for (int g = 0; g < 4; g++) {
        float e0 = __builtin_amdgcn_exp2f(sT[m][g][0]);
        float e1 = __builtin_amdgcn_exp2f(sT[m][g][1]);
        float e2 = __builtin_amdgcn_exp2f(sT[m][g][2]);
        float e3 = __builtin_amdgcn_exp2f(sT[m][g][3]);
        w0[g] = pk2u(e0, e1);
        w1[g] = pk2u(e2, e3);
      }
      plswap(w0[0], w0[1]);
      plswap(w1[0], w1[1]);
      plswap(w0[2], w0[3]);
      plswap(w1[2], w1[3]);
      pa[m][0] = mk8(w0[0], w1[0], w0[1], w1[1]);
      pa[m][1] = mk8(w0[2], w1[2], w0[3], w1[3]);
    }

    // PV: A=V^T rows d, k=keys (qsw-permuted to match pa)
    __builtin_amdgcn_s_setprio(1);
#pragma unroll
    for (int g = 0; g < 4; g++) {
      const unsigned short* vb = Vt0 + (size_t)(g * 16) * Nn;
      f16x8 vf0 = *(const f16x8*)vb;
      f16x8 vf1 = *(const f16x8*)(vb + 32);
#pragma unroll
      for (int m = 0; m < 2; m++) {
        oacc[m][g] = __builtin_amdgcn_mfma_f32_16x16x32_f16(vf0, pa[m][0], oacc[m][g], 0, 0, 0);
        oacc[m][g] = __builtin_amdgcn_mfma_f32_16x16x32_f16(vf1, pa[m][1], oacc[m][g], 0, 0, 0);
      }
    }
    __builtin_amdgcn_s_setprio(0);
  }

#pragma unroll
  for (int m = 0; m < 2; m++) {
    float inv = __builtin_amdgcn_rcpf(__shfl(oacc[m][3][0], l16));
    size_t obase = ((size_t)b * Nn + q0 + wave * 32 + m * 16 + l16) * Cc + h * HD;
#pragma unroll
    for (int g = 0; g < 3; g++) {
      ushort4 sv;
      sv.x = f2h(oacc[m][g][0] * inv);
      sv.y = f2h(oacc[m][g][1] * inv);
      sv.z = f2h(oacc[m][g][2] * inv);
      sv.w = f2h(oacc[m][g][3] * inv);
      *(ushort4*)(obh + obase + g * 16 + quad * 4) = sv;
    }
  }
}

// ---------------------------------------------------------------------------
// Kernel F: projection GEMM, f16 single-term, async global_load_lds staging.
// ---------------------------------------------------------------------------
__global__ __launch_bounds__(256, 4) void proj_mfma(
    const unsigned short* __restrict__ pwh,
    const unsigned short* __restrict__ obh,
    const float* __restrict__ pb, float* __restrict__ out) {
  __shared__ unsigned short Ash[128 * 64];
  __shared__ unsigned short Bsh[128 * 64];
  const int b  = blockIdx.z;
  const int c0m = blockIdx.y * 128;
  const int n0 = blockIdx.x * 128;
  const int tid = threadIdx.x;
  const int wave = tid >> 6, lane = tid & 63;
  const int quad = lane >> 4, l16 = lane & 15;
  const int wm = (wave >> 1) * 64, wn = (wave & 1) * 64;

  f32x4 acc[4][4];
#pragma unroll
  for (int mi = 0; mi < 4; mi++)
#pragma unroll
    for (int ni = 0; ni < 4; ni++) acc[mi][ni] = (f32x4){0.f, 0.f, 0.f, 0.f};

  const int sw = l16 & 7;

  for (int j0 = 0; j0 < Cc; j0 += 64) {
    __syncthreads();
#pragma unroll
    for (int s = 0; s < 4; s++) {
      int r  = s * 32 + wave * 8 + (lane >> 3);
      int cg = ((lane & 7) ^ (lane >> 3)) * 8;
      gload_lds16(pwh + (size_t)(c0m + r) * Cc + j0 + cg,
                  &Ash[(s * 32 + wave * 8) * 64]);
      gload_lds16(obh + ((size_t)b * Nn + n0 + r) * Cc + j0 + cg,
                  &Bsh[(s * 32 + wave * 8) * 64]);
    }
    __syncthreads();

#pragma unroll
    for (int ks = 0; ks < 64; ks += 32) {
      const int ach = (((ks >> 3) + quad) ^ sw) * 8;
      f16x8 ah[4], bh[4];
#pragma unroll
      for (int mi = 0; mi < 4; mi++)
        ah[mi] = *(const f16x8*)&Ash[(wm + mi * 16 + l16) * 64 + ach];
#pragma unroll
      for (int ni = 0; ni < 4; ni++)
        bh[ni] = *(const f16x8*)&Bsh[(wn + ni * 16 + l16) * 64 + ach];
#pragma unroll
      for (int mi = 0; mi < 4; mi++)
#pragma unroll
        for (int ni = 0; ni < 4; ni++)
          acc[mi][ni] = __builtin_amdgcn_mfma_f32_16x16x32_f16(ah[mi], bh[ni], acc[mi][ni], 0, 0, 0);
    }
  }

#pragma unroll
  for (int mi = 0; mi < 4; mi++) {
#pragma unroll
    for (int r = 0; r < 4; r++) {
      int c = c0m + wm + mi * 16 + quad * 4 + r;
      float bvv = pb[c];
#pragma unroll
      for (int ni = 0; ni < 4; ni++) {
        int n = n0 + wn + ni * 16 + l16;
        out[((size_t)b * Cc + c) * Nn + n] = acc[mi][ni][r] + bvv;
      }
    }
  }
}

// ---------------------------------------------------------------------------
extern "C" void kernel_launch(void* const* d_in, const int* in_sizes, int n_in,
                              void* d_out, int out_size, void* d_ws, size_t ws_size,
                              hipStream_t stream) {
  const float* x     = (const float*)d_in[0];
  const float* temp  = (const float*)d_in[1];
  const float* qkv_w = (const float*)d_in[2];
  const float* qkv_b = (const float*)d_in[3];
  const float* pw    = (const float*)d_in[4];
  const float* pb    = (const float*)d_in[5];
  float* out = (float*)d_out;

  const size_t QKN = (size_t)Bb * NH * Nn * D64;   // 8,388,608
  const size_t WQN = (size_t)C3 * Cc;              // 442,368
  const size_t PWN = (size_t)Cc * Cc;              // 147,456

  unsigned short* Qh  = (unsigned short*)d_ws;
  unsigned short* Kh  = Qh + QKN;
  unsigned short* VhT = Kh + QKN;                  // [B][NH][64][N]
  unsigned short* Wqh = VhT + QKN;
  unsigned short* Pwh = Wqh + WQN;
  unsigned short* Xth = Pwh + PWN;                 // aliased by Obh after qkv
  unsigned short* Obh = Xth;

  prep_kernel<<<3328, 256, 0, stream>>>(qkv_w, pw, Wqh, Pwh, VhT);
  xsplit_kernel<<<dim3(Nn / 64, Cc / 64, Bb), 256, 0, stream>>>(x, Xth);
  qkv_mfma<<<dim3(Nn / 128, C3 / 96, Bb), 256, 0, stream>>>(Wqh, Xth, qkv_b, temp, Qh, Kh, VhT);
  attn_mfma<<<1024, 256, 0, stream>>>(Qh, Kh, VhT, Obh);
  proj_mfma<<<dim3(Nn / 128, Cc / 128, Bb), 256, 0, stream>>>(Pwh, Obh, pb, out);
}

// Round 7
// 154.031 us; speedup vs baseline: 1.5292x; 1.5292x over previous
//
#include <hip/hip_runtime.h>
#include <hip/hip_bf16.h>

// Problem constants
#define Bb   16
#define Cc   384
#define Nn   1024
#define NH   8
#define HD   48
#define C3   1152
#define D64  64          // padded head dim for MFMA

typedef _Float16 f16x8 __attribute__((ext_vector_type(8)));
typedef __fp16   h16x2 __attribute__((ext_vector_type(2)));
typedef float    f32x4 __attribute__((ext_vector_type(4)));
typedef unsigned short ushort8 __attribute__((ext_vector_type(8)));

__device__ inline unsigned short f2h(float f) {
  union { _Float16 h; unsigned short u; } cv;
  cv.h = (_Float16)f;            // v_cvt_f16_f32, RNE
  return cv.u;
}
__device__ inline unsigned int pk2u(float a, float b) {
  union { h16x2 v; unsigned int u; } cv;
  cv.v = __builtin_amdgcn_cvt_pkrtz(a, b);   // v_cvt_pkrtz_f16_f32
  return cv.u;
}
// v_permlane16_swap_b32: a.row1<->b.row0, a.row3<->b.row2 (16-lane rows)
__device__ inline void plswap(unsigned int &a, unsigned int &b) {
  asm("v_permlane16_swap_b32 %0, %1" : "+v"(a), "+v"(b));
}
__device__ inline f16x8 mk8(unsigned int a, unsigned int b,
                            unsigned int c, unsigned int d) {
  union { unsigned int u[4]; f16x8 h; } cv;
  cv.u[0] = a; cv.u[1] = b; cv.u[2] = c; cv.u[3] = d;
  return cv.h;
}

// async 16B global->LDS; lds dest = wave-uniform base + lane*16.
__device__ inline void gload_lds16(const unsigned short* g, unsigned short* l) {
  __builtin_amdgcn_global_load_lds(
      (const __attribute__((address_space(1))) void*)g,
      (__attribute__((address_space(3))) void*)l, 16, 0, 0);
}

// ---------------------------------------------------------------------------
// Kernel AB (merged): blocks 0..3327 = prep (weights fp32->f16, VhT pad rows);
// blocks 3328..4863 = xsplit (x [B][C][N] fp32 -> xT [B][N][C] f16).
// Merged to cut one launch gap; the two memory-bound jobs overlap.
// ---------------------------------------------------------------------------
__global__ __launch_bounds__(256) void prep_xsplit_kernel(
    const float* __restrict__ qkv_w, const float* __restrict__ pw,
    const float* __restrict__ x,
    unsigned short* __restrict__ wqh, unsigned short* __restrict__ pwh,
    unsigned short* __restrict__ vt, unsigned short* __restrict__ xh) {
  __shared__ float tile[64][65];
  const int bid = blockIdx.x;
  if (bid < 1728) {
    int i = bid * 256 + threadIdx.x;
    wqh[i] = f2h(qkv_w[i]);
  } else if (bid < 2304) {
    int i = (bid - 1728) * 256 + threadIdx.x;
    pwh[i] = f2h(pw[i]);
  } else if (bid < 3328) {
    int idx8 = (bid - 2304) * 256 + threadIdx.x;   // 262144 ushort8 chunks
    int bh = idx8 >> 11;
    int rem = idx8 & 2047;
    int row = 48 + (rem >> 7);
    int col = (rem & 127) * 8;
    unsigned short fill = (row == 48) ? (unsigned short)0x3C00 : (unsigned short)0;
    ushort8 v;
#pragma unroll
    for (int j = 0; j < 8; j++) v[j] = fill;
    *(ushort8*)(vt + (size_t)bh * D64 * Nn + (size_t)row * Nn + col) = v;
  } else {
    const int xb = bid - 3328;            // 1536 blocks: [b][c-tile][n-tile]
    const int b  = xb / 96;
    const int rem = xb % 96;
    const int c0 = (rem / 16) * 64;
    const int n0 = (rem % 16) * 64;
    const int t  = threadIdx.x;
    const int rl = t >> 2, sc = (t & 3) * 16;
    {
      const float* src = x + ((size_t)b * Cc + c0 + rl) * Nn + n0 + sc;
#pragma unroll
      for (int i = 0; i < 4; i++) {
        float4 v = *(const float4*)(src + i * 4);
        tile[rl][sc + i * 4 + 0] = v.x; tile[rl][sc + i * 4 + 1] = v.y;
        tile[rl][sc + i * 4 + 2] = v.z; tile[rl][sc + i * 4 + 3] = v.w;
      }
    }
    __syncthreads();
    {
      ushort8 h0, h1;
#pragma unroll
      for (int i = 0; i < 8; i++) h0[i] = f2h(tile[sc + i][rl]);
#pragma unroll
      for (int i = 0; i < 8; i++) h1[i] = f2h(tile[sc + 8 + i][rl]);
      size_t dst = ((size_t)b * Nn + n0 + rl) * Cc + c0 + sc;
      *(ushort8*)(xh + dst) = h0; *(ushort8*)(xh + dst + 8) = h1;
    }
  }
}

// ---------------------------------------------------------------------------
// Kernel C: QKV GEMM, f16 MFMA, j-tile = 96 = exactly 2 heads.
//  q-epilogue folds temp[h]*log2e into the L2-norm scale, so attn's exp2
//  input is the raw MFMA output (no per-element fma on the attn hot path).
// ---------------------------------------------------------------------------
__global__ __launch_bounds__(256, 4) void qkv_mfma(
    const unsigned short* __restrict__ wh,
    const unsigned short* __restrict__ xh,
    const float* __restrict__ bias, const float* __restrict__ temp,
    unsigned short* __restrict__ qh, unsigned short* __restrict__ kh,
    unsigned short* __restrict__ vt) {
  __shared__ unsigned short lds[128 * 136];
  unsigned short* Ash = lds;          // [96][64]
  unsigned short* Bsh = lds + 6144;   // [128][64]

  const int b  = blockIdx.z;
  const int yb = blockIdx.y;
  const int j0 = yb * 96;
  const int n0 = blockIdx.x * 128;
  const int tid = threadIdx.x;
  const int wave = tid >> 6, lane = tid & 63;
  const int quad = lane >> 4, l16 = lane & 15;
  const int wm = (wave >> 1) * 48, wn = (wave & 1) * 64;
  const int hs = wave >> 1;           // head-sub within the 2-head tile

  f32x4 acc[3][4];
#pragma unroll
  for (int mi = 0; mi < 3; mi++)
#pragma unroll
    for (int ni = 0; ni < 4; ni++) acc[mi][ni] = (f32x4){0.f, 0.f, 0.f, 0.f};

  const int sw = l16 & 7;

  for (int c0 = 0; c0 < Cc; c0 += 64) {
    __syncthreads();
#pragma unroll
    for (int s = 0; s < 3; s++) {
      int r  = s * 32 + wave * 8 + (lane >> 3);
      int cg = ((lane & 7) ^ (lane >> 3)) * 8;
      gload_lds16(wh + (size_t)(j0 + r) * Cc + c0 + cg,
                  &Ash[(s * 32 + wave * 8) * 64]);
    }
#pragma unroll
    for (int s = 0; s < 4; s++) {
      int r  = s * 32 + wave * 8 + (lane >> 3);
      int cg = ((lane & 7) ^ (lane >> 3)) * 8;
      gload_lds16(xh + ((size_t)b * Nn + n0 + r) * Cc + c0 + cg,
                  &Bsh[(s * 32 + wave * 8) * 64]);
    }
    __syncthreads();

#pragma unroll
    for (int ks = 0; ks < 64; ks += 32) {
      const int ach = (((ks >> 3) + quad) ^ sw) * 8;
      f16x8 ah[3], bh[4];
#pragma unroll
      for (int mi = 0; mi < 3; mi++)
        ah[mi] = *(const f16x8*)&Ash[(wm + mi * 16 + l16) * 64 + ach];
#pragma unroll
      for (int ni = 0; ni < 4; ni++)
        bh[ni] = *(const f16x8*)&Bsh[(wn + ni * 16 + l16) * 64 + ach];
#pragma unroll
      for (int mi = 0; mi < 3; mi++)
#pragma unroll
        for (int ni = 0; ni < 4; ni++)
          acc[mi][ni] = __builtin_amdgcn_mfma_f32_16x16x32_f16(ah[mi], bh[ni], acc[mi][ni], 0, 0, 0);
    }
  }

  const int part = yb >> 2;           // 0=q, 1=k, 2=v
  const int tq   = yb & 3;            // tile within part -> heads 2tq, 2tq+1
  float bv[3][4];
#pragma unroll
  for (int mi = 0; mi < 3; mi++)
#pragma unroll
    for (int r = 0; r < 4; r++)
      bv[mi][r] = bias[j0 + wm + mi * 16 + quad * 4 + r];

  if (part < 2) {
    unsigned short* dst = part ? kh : qh;
    // q rows additionally carry temp[h]*log2(e)
    const float tmul = part ? 1.0f : temp[2 * tq + hs] * 1.44269504f;
    __syncthreads();   // lds reuse: staging -> transpose buffer
#pragma unroll
    for (int ni = 0; ni < 4; ni++) {
      float vals[3][4];
      float ss = 0.f;
#pragma unroll
      for (int mi = 0; mi < 3; mi++)
#pragma unroll
        for (int r = 0; r < 4; r++) {
          float v = acc[mi][ni][r] + bv[mi][r];
          vals[mi][r] = v; ss += v * v;
        }
      ss += __shfl_xor(ss, 16);       // sum the 4 quads -> full 48-d row norm
      ss += __shfl_xor(ss, 32);
      float scale = tmul / fmaxf(sqrtf(ss), 1e-12f);
      int n = wn + ni * 16 + l16;
#pragma unroll
      for (int mi = 0; mi < 3; mi++) {
        ushort4 sv;
        sv.x = f2h(vals[mi][0] * scale);
        sv.y = f2h(vals[mi][1] * scale);
        sv.z = f2h(vals[mi][2] * scale);
        sv.w = f2h(vals[mi][3] * scale);
        *(ushort4*)&lds[n * 136 + hs * 64 + mi * 16 + quad * 4] = sv;
      }
    }
    {  // zero the d=48..63 pads (full-line stores below include them)
      int n = tid >> 1, h2 = tid & 1;
      ushort8 z = {0, 0, 0, 0, 0, 0, 0, 0};
      *(ushort8*)&lds[n * 136 + h2 * 64 + 48] = z;
      *(ushort8*)&lds[n * 136 + h2 * 64 + 56] = z;
    }
    __syncthreads();
#pragma unroll
    for (int it = 0; it < 8; it++) {
      int n = wave * 32 + it * 4 + (lane >> 4);
      int chunk = lane & 15;
      int hs3 = chunk >> 3, c8 = (chunk & 7) * 8;
      int h = 2 * tq + hs3;
      ushort8 v = *(const ushort8*)&lds[n * 136 + hs3 * 64 + c8];
      *(ushort8*)(dst + ((size_t)(b * NH + h) * Nn + n0 + n) * D64 + c8) = v;
    }
  } else {
    const int h = 2 * tq + hs;
#pragma unroll
    for (int mi = 0; mi < 3; mi++) {
#pragma unroll
      for (int r = 0; r < 4; r++) {
        int d = mi * 16 + quad * 4 + r;
        unsigned short* vrow = vt + ((size_t)(b * NH + h) * D64 + d) * Nn;
#pragma unroll
        for (int ni = 0; ni < 4; ni++) {
          int n = n0 + wn + ni * 16 + l16;
          vrow[n] = f2h(acc[mi][ni][r] + bv[mi][r]);
        }
      }
    }
  }
}

// ---------------------------------------------------------------------------
// Kernel E: f16 MFMA flash attention v3 (reverted best: R3 structure).
//  - K/V double-buffered via async global_load_lds; 1 barrier/iter.
//  - P stays in registers (cvt_pkrtz + permlane16_swap, V read qsw-permuted).
//  - temp*log2e pre-folded into Q; denominator via ones-column of V^T.
//  - s_setprio(1) around MFMA clusters.
// ---------------------------------------------------------------------------
__global__ __launch_bounds__(256, 4) void attn_mfma(
    const unsigned short* __restrict__ qh, const unsigned short* __restrict__ kh,
    const unsigned short* __restrict__ vt,
    unsigned short* __restrict__ obh) {
  __shared__ __align__(16) unsigned short Kt[2][64 * 64];
  __shared__ __align__(16) unsigned short Vt[2][64 * 64];

  const int bid = blockIdx.x;
  const int hb = bid & 127;            // same head -> same XCD (bid%8 const)
  const int q0 = (bid >> 7) * 128;
  const int b = hb >> 3, h = hb & 7;
  const int tid = threadIdx.x;
  const int wave = tid >> 6, lane = tid & 63;
  const int quad = lane >> 4, l16 = lane & 15;
  const int qsw = ((quad & 1) << 1) | (quad >> 1);   // swap quads 1<->2
  const int sx = (l16 & 7) * 8;                      // read-side XOR (ushorts)

  const size_t headQ = ((size_t)(b * NH + h) * Nn) * D64;
  const unsigned short* Qg = qh + headQ + (size_t)(q0 + wave * 32) * D64;
  const unsigned short* Kg = kh + headQ;
  const unsigned short* Vg = vt + ((size_t)(b * NH + h) * D64) * Nn;

  f16x8 qa0[2], qa1[2];
#pragma unroll
  for (int m = 0; m < 2; m++) {
    qa0[m] = *(const f16x8*)(Qg + (m * 16 + l16) * D64 + quad * 8);
    qa1[m] = *(const f16x8*)(Qg + (m * 16 + l16) * D64 + quad * 8 + 32);
  }

  f32x4 oacc[2][4];
#pragma unroll
  for (int m = 0; m < 2; m++)
#pragma unroll
    for (int g = 0; g < 4; g++) oacc[m][g] = (f32x4){0.f, 0.f, 0.f, 0.f};
  const f32x4 zf = (f32x4){0.f, 0.f, 0.f, 0.f};

  // DMA staging geometry: per wave 2 instrs K + 2 instrs V, 8 rows x 128B each
  const int srow = lane >> 3;                       // 0..7
  const int scol = ((lane & 7) ^ srow) * 8;         // pre-swizzled global col
  const int r0 = wave * 16;
  const unsigned short* KgS = Kg + (size_t)(r0 + srow) * D64 + scol;
  const unsigned short* VgS = Vg + (size_t)(r0 + srow) * Nn + scol;

  // prologue: tile 0 -> buf 0
  gload_lds16(KgS,           &Kt[0][r0 * 64]);
  gload_lds16(KgS + 8 * D64, &Kt[0][(r0 + 8) * 64]);
  gload_lds16(VgS,           &Vt[0][r0 * 64]);
  gload_lds16(VgS + 8 * Nn,  &Vt[0][(r0 + 8) * 64]);

  for (int kt = 0; kt < Nn / 64; kt++) {
    __syncthreads();          // drains vmcnt(0): tile kt resident, prev reads done
    const int cur = kt & 1;
    if (kt < Nn / 64 - 1) {   // issue tile kt+1 into the other buffer (async)
      const unsigned short* kn = KgS + (size_t)(kt + 1) * 64 * D64;
      const unsigned short* vn = VgS + (size_t)(kt + 1) * 64;
      gload_lds16(kn,           &Kt[cur ^ 1][r0 * 64]);
      gload_lds16(kn + 8 * D64, &Kt[cur ^ 1][(r0 + 8) * 64]);
      gload_lds16(vn,           &Vt[cur ^ 1][r0 * 64]);
      gload_lds16(vn + 8 * Nn,  &Vt[cur ^ 1][(r0 + 8) * 64]);
    }
    const unsigned short* Kl = Kt[cur];
    const unsigned short* Vl = Vt[cur];

    // QK^T (swapped): sT[m][g] = S^T[key g*16+quad*4+r][query m*16+l16]
    f32x4 sT[2][4];
    __builtin_amdgcn_s_setprio(1);
#pragma unroll
    for (int g = 0; g < 4; g++) {
      const unsigned short* kb = Kl + (g * 16 + l16) * 64;
      const int go = (quad * 8) ^ sx;
      f16x8 kf0 = *(const f16x8*)&kb[go];
      f16x8 kf1 = *(const f16x8*)&kb[go ^ 32];
#pragma unroll
      for (int m = 0; m < 2; m++) {
        f32x4 s = __builtin_amdgcn_mfma_f32_16x16x32_f16(kf0, qa0[m], zf, 0, 0, 0);
        sT[m][g] = __builtin_amdgcn_mfma_f32_16x16x32_f16(kf1, qa1[m], s, 0, 0, 0);
      }
    }
    __builtin_amdgcn_s_setprio(0);

    // exp2 + pack: w0 = keys(4q,4q+1), w1 = keys(4q+2,4q+3) per g-block
    unsigned int w0[2][4], w1[2][4];
#pragma unroll
    for (int m = 0; m < 2; m++)
#pragma unroll
      for (int g = 0; g < 4; g++) {
        float e0 = __builtin_amdgcn_exp2f(sT[m][g][0]);
        float e1 = __builtin_amdgcn_exp2f(sT[m][g][1]);
        float e2 = __builtin_amdgcn_exp2f(sT[m][g][2]);
        float e3 = __builtin_amdgcn_exp2f(sT[m][g][3]);
        w0[m][g] = pk2u(e0, e1);
        w1[m][g] = pk2u(e2, e3);
      }

    // quad redistribution: after swap, fragment key-blocks sit at quads
    // [0,16,8,24] -> V reads use qsw (1<->2) to match.
    f16x8 pa[2][2];
#pragma unroll
    for (int m = 0; m < 2; m++) {
      plswap(w0[m][0], w0[m][1]);
      plswap(w1[m][0], w1[m][1]);
      plswap(w0[m][2], w0[m][3]);
      plswap(w1[m][2], w1[m][3]);
      pa[m][0] = mk8(w0[m][0], w1[m][0], w0[m][1], w1[m][1]);
      pa[m][1] = mk8(w0[m][2], w1[m][2], w0[m][3], w1[m][3]);
    }

    // PV: A=V^T rows d, k=keys (qsw-permuted to match pa)
    __builtin_amdgcn_s_setprio(1);
#pragma unroll
    for (int g = 0; g < 4; g++) {
      const unsigned short* vb = Vl + (g * 16 + l16) * 64;
      const int go = (qsw * 8) ^ sx;
      f16x8 vf0 = *(const f16x8*)&vb[go];
      f16x8 vf1 = *(const f16x8*)&vb[go ^ 32];
#pragma unroll
      for (int m = 0; m < 2; m++) {
        oacc[m][g] = __builtin_amdgcn_mfma_f32_16x16x32_f16(vf0, pa[m][0], oacc[m][g], 0, 0, 0);
        oacc[m][g] = __builtin_amdgcn_mfma_f32_16x16x32_f16(vf1, pa[m][1], oacc[m][g], 0, 0, 0);
      }
    }
    __builtin_amdgcn_s_setprio(0);
  }

#pragma unroll
  for (int m = 0; m < 2; m++) {
    float inv = __builtin_amdgcn_rcpf(__shfl(oacc[m][3][0], l16));
    size_t obase = ((size_t)b * Nn + q0 + wave * 32 + m * 16 + l16) * Cc + h * HD;
#pragma unroll
    for (int g = 0; g < 3; g++) {
      ushort4 sv;
      sv.x = f2h(oacc[m][g][0] * inv);
      sv.y = f2h(oacc[m][g][1] * inv);
      sv.z = f2h(oacc[m][g][2] * inv);
      sv.w = f2h(oacc[m][g][3] * inv);
      *(ushort4*)(obh + obase + g * 16 + quad * 4) = sv;
    }
  }
}

// ---------------------------------------------------------------------------
// Kernel F: projection GEMM, f16 single-term, async global_load_lds staging.
// ---------------------------------------------------------------------------
__global__ __launch_bounds__(256, 4) void proj_mfma(
    const unsigned short* __restrict__ pwh,
    const unsigned short* __restrict__ obh,
    const float* __restrict__ pb, float* __restrict__ out) {
  __shared__ unsigned short Ash[128 * 64];
  __shared__ unsigned short Bsh[128 * 64];
  const int b  = blockIdx.z;
  const int c0m = blockIdx.y * 128;
  const int n0 = blockIdx.x * 128;
  const int tid = threadIdx.x;
  const int wave = tid >> 6, lane = tid & 63;
  const int quad = lane >> 4, l16 = lane & 15;
  const int wm = (wave >> 1) * 64, wn = (wave & 1) * 64;

  f32x4 acc[4][4];
#pragma unroll
  for (int mi = 0; mi < 4; mi++)
#pragma unroll
    for (int ni = 0; ni < 4; ni++) acc[mi][ni] = (f32x4){0.f, 0.f, 0.f, 0.f};

  const int sw = l16 & 7;

  for (int j0 = 0; j0 < Cc; j0 += 64) {
    __syncthreads();
#pragma unroll
    for (int s = 0; s < 4; s++) {
      int r  = s * 32 + wave * 8 + (lane >> 3);
      int cg = ((lane & 7) ^ (lane >> 3)) * 8;
      gload_lds16(pwh + (size_t)(c0m + r) * Cc + j0 + cg,
                  &Ash[(s * 32 + wave * 8) * 64]);
      gload_lds16(obh + ((size_t)b * Nn + n0 + r) * Cc + j0 + cg,
                  &Bsh[(s * 32 + wave * 8) * 64]);
    }
    __syncthreads();

#pragma unroll
    for (int ks = 0; ks < 64; ks += 32) {
      const int ach = (((ks >> 3) + quad) ^ sw) * 8;
      f16x8 ah[4], bh[4];
#pragma unroll
      for (int mi = 0; mi < 4; mi++)
        ah[mi] = *(const f16x8*)&Ash[(wm + mi * 16 + l16) * 64 + ach];
#pragma unroll
      for (int ni = 0; ni < 4; ni++)
        bh[ni] = *(const f16x8*)&Bsh[(wn + ni * 16 + l16) * 64 + ach];
#pragma unroll
      for (int mi = 0; mi < 4; mi++)
#pragma unroll
        for (int ni = 0; ni < 4; ni++)
          acc[mi][ni] = __builtin_amdgcn_mfma_f32_16x16x32_f16(ah[mi], bh[ni], acc[mi][ni], 0, 0, 0);
    }
  }

#pragma unroll
  for (int mi = 0; mi < 4; mi++) {
#pragma unroll
    for (int r = 0; r < 4; r++) {
      int c = c0m + wm + mi * 16 + quad * 4 + r;
      float bvv = pb[c];
#pragma unroll
      for (int ni = 0; ni < 4; ni++) {
        int n = n0 + wn + ni * 16 + l16;
        out[((size_t)b * Cc + c) * Nn + n] = acc[mi][ni][r] + bvv;
      }
    }
  }
}

// ---------------------------------------------------------------------------
extern "C" void kernel_launch(void* const* d_in, const int* in_sizes, int n_in,
                              void* d_out, int out_size, void* d_ws, size_t ws_size,
                              hipStream_t stream) {
  const float* x     = (const float*)d_in[0];
  const float* temp  = (const float*)d_in[1];
  const float* qkv_w = (const float*)d_in[2];
  const float* qkv_b = (const float*)d_in[3];
  const float* pw    = (const float*)d_in[4];
  const float* pb    = (const float*)d_in[5];
  float* out = (float*)d_out;

  const size_t QKN = (size_t)Bb * NH * Nn * D64;   // 8,388,608
  const size_t WQN = (size_t)C3 * Cc;              // 442,368
  const size_t PWN = (size_t)Cc * Cc;              // 147,456

  unsigned short* Qh  = (unsigned short*)d_ws;
  unsigned short* Kh  = Qh + QKN;
  unsigned short* VhT = Kh + QKN;                  // [B][NH][64][N]
  unsigned short* Wqh = VhT + QKN;
  unsigned short* Pwh = Wqh + WQN;
  unsigned short* Xth = Pwh + PWN;                 // aliased by Obh after qkv
  unsigned short* Obh = Xth;

  prep_xsplit_kernel<<<4864, 256, 0, stream>>>(qkv_w, pw, x, Wqh, Pwh, VhT, Xth);
  qkv_mfma<<<dim3(Nn / 128, C3 / 96, Bb), 256, 0, stream>>>(Wqh, Xth, qkv_b, temp, Qh, Kh, VhT);
  attn_mfma<<<1024, 256, 0, stream>>>(Qh, Kh, VhT, Obh);
  proj_mfma<<<dim3(Nn / 128, Cc / 128, Bb), 256, 0, stream>>>(Pwh, Obh, pb, out);
}